// Round 1
// baseline (784.172 us; speedup 1.0000x reference)
//
#include <hip/hip_runtime.h>

#define SLEN 1024
#define BATCH 2
#define NHEADS 16
#define HD 64
#define HALF 32
#define DEPTH 6

// ---------------------------------------------------------------------------
// GEMM: C[2048,1024] = A[2048,1024] @ W[1024,1024]  (fp32, 64x64 tile, BK=32)
// ---------------------------------------------------------------------------
__device__ __forceinline__ void gemm_body(const float* __restrict__ A,
                                          const float* __restrict__ W,
                                          float* __restrict__ C) {
  __shared__ float As[32][68];  // As[k][m], pad 68 keeps float4 align + banks spread
  __shared__ float Bs[32][68];  // Bs[k][n]
  const int t  = threadIdx.x;
  const int bm = blockIdx.y * 64;
  const int bn = blockIdx.x * 64;
  const int tm = (t >> 4) * 4;
  const int tn = (t & 15) * 4;
  const int ai = t >> 2;            // A tile row 0..63
  const int ac = (t & 3) * 8;       // A tile col start {0,8,16,24}
  const int bk = t >> 3;            // B tile row 0..31
  const int bc = (t & 7) * 8;       // B tile col start
  float acc[4][4] = {};
  for (int k0 = 0; k0 < 1024; k0 += 32) {
    const float* ap = A + (size_t)(bm + ai) * 1024 + k0 + ac;
    const float* bp = W + (size_t)(k0 + bk) * 1024 + bn + bc;
    float4 a0 = *(const float4*)(ap);
    float4 a1 = *(const float4*)(ap + 4);
    float4 b0 = *(const float4*)(bp);
    float4 b1 = *(const float4*)(bp + 4);
    __syncthreads();  // previous iteration's compute must be done before overwrite
    As[ac + 0][ai] = a0.x; As[ac + 1][ai] = a0.y;
    As[ac + 2][ai] = a0.z; As[ac + 3][ai] = a0.w;
    As[ac + 4][ai] = a1.x; As[ac + 5][ai] = a1.y;
    As[ac + 6][ai] = a1.z; As[ac + 7][ai] = a1.w;
    *(float4*)&Bs[bk][bc]     = b0;
    *(float4*)&Bs[bk][bc + 4] = b1;
    __syncthreads();
    #pragma unroll
    for (int kk = 0; kk < 32; ++kk) {
      float4 av = *(const float4*)&As[kk][tm];
      float4 bv = *(const float4*)&Bs[kk][tn];
      float a4[4] = {av.x, av.y, av.z, av.w};
      float b4[4] = {bv.x, bv.y, bv.z, bv.w};
      #pragma unroll
      for (int i = 0; i < 4; ++i)
        #pragma unroll
        for (int j = 0; j < 4; ++j)
          acc[i][j] = fmaf(a4[i], b4[j], acc[i][j]);
    }
  }
  #pragma unroll
  for (int i = 0; i < 4; ++i) {
    float4 o = {acc[i][0], acc[i][1], acc[i][2], acc[i][3]};
    *(float4*)(C + (size_t)(bm + tm + i) * 1024 + bn + tn) = o;
  }
}

__global__ __launch_bounds__(256) void gemm_qkv(const float* __restrict__ x,
    const float* __restrict__ wq, const float* __restrict__ wk,
    const float* __restrict__ wv, float* __restrict__ q,
    float* __restrict__ k, float* __restrict__ v) {
  const float* W = (blockIdx.z == 0) ? wq : (blockIdx.z == 1) ? wk : wv;
  float*       C = (blockIdx.z == 0) ? q  : (blockIdx.z == 1) ? k  : v;
  gemm_body(x, W, C);
}

__global__ __launch_bounds__(256) void gemm_o(const float* __restrict__ A,
    const float* __restrict__ W, float* __restrict__ C) {
  gemm_body(A, W, C);
}

// ---------------------------------------------------------------------------
// RoPE instruction sequence: one thread per (b,s,h); 64-elem head vec in regs.
// Sequence per depth d: rot_H(cos1,sin1,Hm[d]); rot_B(cos1,sin1,Bm[d,0]);
//                       rot_B(cos2,sin2,Bm[d,1])
// rot_H pairs (2j,2j+1); rot_B pairs (j, j+32).
// ---------------------------------------------------------------------------
__global__ __launch_bounds__(256) void rope_kernel(float* __restrict__ q,
    float* __restrict__ k, const int* __restrict__ Hm,
    const int* __restrict__ Bm, const float* __restrict__ fc,
    const float* __restrict__ fs) {
  __shared__ float c1[32], s1[32], c2[32], s2[32];
  const int t = threadIdx.x;
  if (t < 32) {
    c1[t] = fc[32 + t]; s1[t] = fs[32 + t];   // freqs row 1
    c2[t] = fc[64 + t]; s2[t] = fs[64 + t];   // freqs row 2
  }
  __syncthreads();
  const int gid = blockIdx.x * 256 + t;   // flattened (b,s,h), 0..32767
  const int bs  = gid >> 4;               // b*1024 + s
  float* base = (blockIdx.y == 0 ? q : k) + (size_t)gid * 64;
  float vv[64];
  #pragma unroll
  for (int i = 0; i < 16; ++i) *(float4*)&vv[i * 4] = *(const float4*)(base + i * 4);
  #pragma unroll 1
  for (int d = 0; d < DEPTH; ++d) {
    if (Hm[d * (BATCH * SLEN) + bs] != 0) {
      #pragma unroll
      for (int j = 0; j < 32; ++j) {
        float re = vv[2 * j], im = vv[2 * j + 1];
        vv[2 * j]     = re * c1[j] - im * s1[j];
        vv[2 * j + 1] = re * s1[j] + im * c1[j];
      }
    }
    if (Bm[(d * 2 + 0) * (BATCH * SLEN) + bs] != 0) {
      #pragma unroll
      for (int j = 0; j < 32; ++j) {
        float re = vv[j], im = vv[j + 32];
        vv[j]      = re * c1[j] - im * s1[j];
        vv[j + 32] = re * s1[j] + im * c1[j];
      }
    }
    if (Bm[(d * 2 + 1) * (BATCH * SLEN) + bs] != 0) {
      #pragma unroll
      for (int j = 0; j < 32; ++j) {
        float re = vv[j], im = vv[j + 32];
        vv[j]      = re * c2[j] - im * s2[j];
        vv[j + 32] = re * s2[j] + im * c2[j];
      }
    }
  }
  #pragma unroll
  for (int i = 0; i < 16; ++i) *(float4*)(base + i * 4) = *(const float4*)&vv[i * 4];
}

// ---------------------------------------------------------------------------
// Attention: block = (b,h, 8 q-rows). Full score rows (8x1024) live in LDS,
// so plain (non-online) softmax. K/V staged in 64-row chunks.
// ---------------------------------------------------------------------------
__global__ __launch_bounds__(256) void attn_kernel(const float* __restrict__ q,
    const float* __restrict__ k, const float* __restrict__ v,
    const int* __restrict__ masks, float* __restrict__ out) {
  __shared__ float qs[8][68];
  __shared__ float ks[64][68];
  __shared__ float sc[8][1028];   // pad 1028: rows land in distinct banks
  const int t  = threadIdx.x;
  const int b  = blockIdx.y >> 4;
  const int h  = blockIdx.y & 15;
  const int s0 = blockIdx.x * 8;
  const size_t headbase = (size_t)b * SLEN * 1024 + (size_t)h * HD;

  if (t < 128) {
    int r = t >> 4, d4 = (t & 15) * 4;
    *(float4*)&qs[r][d4] =
        *(const float4*)(q + headbase + (size_t)(s0 + r) * 1024 + d4);
  }

  const int r  = t & 7;
  const int kg = t >> 3;   // 0..31
  for (int kc = 0; kc < SLEN; kc += 64) {
    __syncthreads();
    #pragma unroll
    for (int j = 0; j < 4; ++j) {
      int idx = t + 256 * j;                 // 0..1023
      int kk = idx >> 4, d4 = (idx & 15) * 4;
      *(float4*)&ks[kk][d4] =
          *(const float4*)(k + headbase + (size_t)(kc + kk) * 1024 + d4);
    }
    __syncthreads();
    float acc[2] = {0.f, 0.f};
    #pragma unroll
    for (int d = 0; d < 64; d += 4) {
      float4 qf = *(const float4*)&qs[r][d];
      #pragma unroll
      for (int j = 0; j < 2; ++j) {
        float4 kf = *(const float4*)&ks[kg + 32 * j][d];
        acc[j] += qf.x * kf.x + qf.y * kf.y + qf.z * kf.z + qf.w * kf.w;
      }
    }
    #pragma unroll
    for (int j = 0; j < 2; ++j) {
      int kk = kg + 32 * j;
      float val = acc[j] * 0.125f;
      if (masks[(size_t)b * SLEN * SLEN + (size_t)(s0 + r) * SLEN + kc + kk] == 0)
        val = -1000000000.0f;
      sc[r][kc + kk] = val;
    }
  }
  __syncthreads();
  // softmax: wave w owns rows 2w, 2w+1
  {
    const int wave = t >> 6, lane = t & 63;
    #pragma unroll
    for (int rr0 = 0; rr0 < 2; ++rr0) {
      const int rr = wave * 2 + rr0;
      float m = -3.0e38f;
      for (int i = lane; i < SLEN; i += 64) m = fmaxf(m, sc[rr][i]);
      #pragma unroll
      for (int off = 32; off > 0; off >>= 1) m = fmaxf(m, __shfl_xor(m, off, 64));
      float sum = 0.f;
      for (int i = lane; i < SLEN; i += 64) {
        float e = __expf(sc[rr][i] - m);
        sc[rr][i] = e;
        sum += e;
      }
      #pragma unroll
      for (int off = 32; off > 0; off >>= 1) sum += __shfl_xor(sum, off, 64);
      float inv = 1.0f / sum;
      for (int i = lane; i < SLEN; i += 64) sc[rr][i] *= inv;
    }
  }
  // PV: thread owns (row r, dims g2, g2+1)
  const int g2 = (t >> 3) * 2;
  float a0 = 0.f, a1 = 0.f;
  for (int kc = 0; kc < SLEN; kc += 64) {
    __syncthreads();
    #pragma unroll
    for (int j = 0; j < 4; ++j) {
      int idx = t + 256 * j;
      int kk = idx >> 4, d4 = (idx & 15) * 4;
      *(float4*)&ks[kk][d4] =
          *(const float4*)(v + headbase + (size_t)(kc + kk) * 1024 + d4);
    }
    __syncthreads();
    #pragma unroll 8
    for (int kk = 0; kk < 64; ++kk) {
      float p   = sc[r][kc + kk];
      float2 vf = *(const float2*)&ks[kk][g2];
      a0 = fmaf(p, vf.x, a0);
      a1 = fmaf(p, vf.y, a1);
    }
  }
  float2 o = {a0, a1};
  *(float2*)(out + headbase + (size_t)(s0 + r) * 1024 + g2) = o;
}

// ---------------------------------------------------------------------------
extern "C" void kernel_launch(void* const* d_in, const int* in_sizes, int n_in,
                              void* d_out, int out_size, void* d_ws, size_t ws_size,
                              hipStream_t stream) {
  const float* x     = (const float*)d_in[0];
  const int*   masks = (const int*)d_in[1];
  const int*   Hm    = (const int*)d_in[2];
  const int*   Bm    = (const int*)d_in[3];
  const float* fc    = (const float*)d_in[4];
  const float* fs    = (const float*)d_in[5];
  const float* wq    = (const float*)d_in[6];
  const float* wk    = (const float*)d_in[7];
  const float* wv    = (const float*)d_in[8];
  const float* wo    = (const float*)d_in[9];
  float* out = (float*)d_out;

  float* q  = (float*)d_ws;              // 2M floats each
  float* k  = q + 2097152;
  float* v  = k + 2097152;
  float* ao = v + 2097152;

  dim3 blk(256);
  gemm_qkv<<<dim3(16, 32, 3), blk, 0, stream>>>(x, wq, wk, wv, q, k, v);
  rope_kernel<<<dim3(128, 2), blk, 0, stream>>>(q, k, Hm, Bm, fc, fs);
  attn_kernel<<<dim3(128, 32), blk, 0, stream>>>(q, k, v, masks, ao);
  gemm_o<<<dim3(16, 32), blk, 0, stream>>>(ao, wo, out);
}

// Round 2
// 415.948 us; speedup vs baseline: 1.8853x; 1.8853x over previous
//
#include <hip/hip_runtime.h>

#define SLEN 1024
#define BATCH 2
#define NHEADS 16
#define HD 64
#define HALF 32
#define DEPTH 6

typedef __bf16 bf8_t __attribute__((ext_vector_type(8)));
typedef float  f4_t  __attribute__((ext_vector_type(4)));

#define MFMA16(a, b, c) __builtin_amdgcn_mfma_f32_16x16x32_bf16(a, b, c, 0, 0, 0)

// ---------------------------------------------------------------------------
// GEMM: C[2048,1024] = A[2048,1024] @ W[1024,1024]  (fp32, 64x64 tile, BK=32)
// TMODE 0: normal row-major C.  TMODE 1: transposed-per-batch write:
//   C_t[(m>>10)*1024 + n][m&1023]  (i.e. vt[b*1024 + n][s])
// ---------------------------------------------------------------------------
template <int TMODE>
__device__ __forceinline__ void gemm_body(const float* __restrict__ A,
                                          const float* __restrict__ W,
                                          float* __restrict__ C) {
  __shared__ float As[32][68];
  __shared__ float Bs[32][68];
  const int t  = threadIdx.x;
  const int bm = blockIdx.y * 64;
  const int bn = blockIdx.x * 64;
  const int tm = (t >> 4) * 4;
  const int tn = (t & 15) * 4;
  const int ai = t >> 2;
  const int ac = (t & 3) * 8;
  const int bk = t >> 3;
  const int bc = (t & 7) * 8;
  float acc[4][4] = {};
  for (int k0 = 0; k0 < 1024; k0 += 32) {
    const float* ap = A + (size_t)(bm + ai) * 1024 + k0 + ac;
    const float* bp = W + (size_t)(k0 + bk) * 1024 + bn + bc;
    float4 a0 = *(const float4*)(ap);
    float4 a1 = *(const float4*)(ap + 4);
    float4 b0 = *(const float4*)(bp);
    float4 b1 = *(const float4*)(bp + 4);
    __syncthreads();
    As[ac + 0][ai] = a0.x; As[ac + 1][ai] = a0.y;
    As[ac + 2][ai] = a0.z; As[ac + 3][ai] = a0.w;
    As[ac + 4][ai] = a1.x; As[ac + 5][ai] = a1.y;
    As[ac + 6][ai] = a1.z; As[ac + 7][ai] = a1.w;
    *(float4*)&Bs[bk][bc]     = b0;
    *(float4*)&Bs[bk][bc + 4] = b1;
    __syncthreads();
    #pragma unroll
    for (int kk = 0; kk < 32; ++kk) {
      float4 av = *(const float4*)&As[kk][tm];
      float4 bv = *(const float4*)&Bs[kk][tn];
      float a4[4] = {av.x, av.y, av.z, av.w};
      float b4[4] = {bv.x, bv.y, bv.z, bv.w};
      #pragma unroll
      for (int i = 0; i < 4; ++i)
        #pragma unroll
        for (int j = 0; j < 4; ++j)
          acc[i][j] = fmaf(a4[i], b4[j], acc[i][j]);
    }
  }
  if (TMODE == 0) {
    #pragma unroll
    for (int i = 0; i < 4; ++i) {
      float4 o = {acc[i][0], acc[i][1], acc[i][2], acc[i][3]};
      *(float4*)(C + (size_t)(bm + tm + i) * 1024 + bn + tn) = o;
    }
  } else {
    #pragma unroll
    for (int i = 0; i < 4; ++i) {
      int m = bm + tm + i;
      size_t brow = (size_t)(m >> 10) * 1024;
      int s = m & 1023;
      #pragma unroll
      for (int j = 0; j < 4; ++j)
        C[(brow + bn + tn + j) * 1024 + s] = acc[i][j];
    }
  }
}

__global__ __launch_bounds__(256) void gemm_qkv(const float* __restrict__ x,
    const float* __restrict__ wq, const float* __restrict__ wk,
    const float* __restrict__ wv, float* __restrict__ q,
    float* __restrict__ k, float* __restrict__ v) {
  if (blockIdx.z == 2) {
    gemm_body<1>(x, wv, v);            // V written transposed: vt[b*1024+d_global][s]
  } else if (blockIdx.z == 1) {
    gemm_body<0>(x, wk, k);
  } else {
    gemm_body<0>(x, wq, q);
  }
}

__global__ __launch_bounds__(256) void gemm_o(const float* __restrict__ A,
    const float* __restrict__ W, float* __restrict__ C) {
  gemm_body<0>(A, W, C);
}

// ---------------------------------------------------------------------------
// RoPE instruction sequence (fp32, unchanged)
// ---------------------------------------------------------------------------
__global__ __launch_bounds__(256) void rope_kernel(float* __restrict__ q,
    float* __restrict__ k, const int* __restrict__ Hm,
    const int* __restrict__ Bm, const float* __restrict__ fc,
    const float* __restrict__ fs) {
  __shared__ float c1[32], s1[32], c2[32], s2[32];
  const int t = threadIdx.x;
  if (t < 32) {
    c1[t] = fc[32 + t]; s1[t] = fs[32 + t];
    c2[t] = fc[64 + t]; s2[t] = fs[64 + t];
  }
  __syncthreads();
  const int gid = blockIdx.x * 256 + t;
  const int bs  = gid >> 4;
  float* base = (blockIdx.y == 0 ? q : k) + (size_t)gid * 64;
  float vv[64];
  #pragma unroll
  for (int i = 0; i < 16; ++i) *(float4*)&vv[i * 4] = *(const float4*)(base + i * 4);
  #pragma unroll 1
  for (int d = 0; d < DEPTH; ++d) {
    if (Hm[d * (BATCH * SLEN) + bs] != 0) {
      #pragma unroll
      for (int j = 0; j < 32; ++j) {
        float re = vv[2 * j], im = vv[2 * j + 1];
        vv[2 * j]     = re * c1[j] - im * s1[j];
        vv[2 * j + 1] = re * s1[j] + im * c1[j];
      }
    }
    if (Bm[(d * 2 + 0) * (BATCH * SLEN) + bs] != 0) {
      #pragma unroll
      for (int j = 0; j < 32; ++j) {
        float re = vv[j], im = vv[j + 32];
        vv[j]      = re * c1[j] - im * s1[j];
        vv[j + 32] = re * s1[j] + im * c1[j];
      }
    }
    if (Bm[(d * 2 + 1) * (BATCH * SLEN) + bs] != 0) {
      #pragma unroll
      for (int j = 0; j < 32; ++j) {
        float re = vv[j], im = vv[j + 32];
        vv[j]      = re * c2[j] - im * s2[j];
        vv[j + 32] = re * s2[j] + im * c2[j];
      }
    }
  }
  #pragma unroll
  for (int i = 0; i < 16; ++i) *(float4*)(base + i * 4) = *(const float4*)&vv[i * 4];
}

// ---------------------------------------------------------------------------
// MFMA flash attention. Block = (b, h, 64 q-rows); 4 waves x 16 q-rows each.
// Chunks of 64 k-columns; online softmax; 16x16x32 bf16 MFMA.
//   QK^T: A = Q[m=q][k=d] (Qs row-major), B = K[n=kcol][k=d] (Ks row-major)
//   PV  : A = P[m=q][k=kc] (Pb row-major), B = V^T[n=d][k=kc] (Vs from vt)
// Mask folded as additive bf16 bias staged in Ms.
// ---------------------------------------------------------------------------
__device__ __forceinline__ void stage16(float4 f0, float4 f1, float4 f2,
                                        float4 f3, __bf16* dst) {
  union { bf8_t v; __bf16 e[8]; } a, b;
  a.e[0] = (__bf16)f0.x; a.e[1] = (__bf16)f0.y; a.e[2] = (__bf16)f0.z; a.e[3] = (__bf16)f0.w;
  a.e[4] = (__bf16)f1.x; a.e[5] = (__bf16)f1.y; a.e[6] = (__bf16)f1.z; a.e[7] = (__bf16)f1.w;
  b.e[0] = (__bf16)f2.x; b.e[1] = (__bf16)f2.y; b.e[2] = (__bf16)f2.z; b.e[3] = (__bf16)f2.w;
  b.e[4] = (__bf16)f3.x; b.e[5] = (__bf16)f3.y; b.e[6] = (__bf16)f3.z; b.e[7] = (__bf16)f3.w;
  *(bf8_t*)dst       = a.v;
  *(bf8_t*)(dst + 8) = b.v;
}

__global__ __launch_bounds__(256) void attn_mfma(const float* __restrict__ q,
    const float* __restrict__ k, const float* __restrict__ vt,
    const int* __restrict__ masks, float* __restrict__ out) {
  __shared__ __bf16 Qs[64][72];
  __shared__ __bf16 Ks[64][72];
  __shared__ __bf16 Vs[64][72];      // Vs[d][kc_local]
  __shared__ __bf16 Ms[64][72];      // additive bias: 0 or -1e9
  __shared__ __bf16 Pb[4][16][72];   // wave-private P

  const int t    = threadIdx.x;
  const int wq   = t >> 6;
  const int lane = t & 63;
  const int ln15 = lane & 15;
  const int quad = lane >> 4;

  const int b  = blockIdx.y >> 4;
  const int h  = blockIdx.y & 15;
  const int s0 = blockIdx.x * 64;

  const size_t qkbase = (size_t)b * (SLEN * 1024) + (size_t)h * HD;
  const size_t vtbase = ((size_t)b * 1024 + h * HD) * SLEN;
  const size_t mbase  = (size_t)b * SLEN * SLEN;

  const int srow = t >> 2;            // staging row 0..63
  const int sc0  = (t & 3) * 16;      // staging col 0..48

  // ---- stage Q tile ----
  {
    const float* src = q + qkbase + (size_t)(s0 + srow) * 1024 + sc0;
    float4 f0 = ((const float4*)src)[0];
    float4 f1 = ((const float4*)src)[1];
    float4 f2 = ((const float4*)src)[2];
    float4 f3 = ((const float4*)src)[3];
    stage16(f0, f1, f2, f3, &Qs[srow][sc0]);
  }
  __syncthreads();
  bf8_t aq0 = *(bf8_t*)&Qs[wq * 16 + ln15][quad * 8];
  bf8_t aq1 = *(bf8_t*)&Qs[wq * 16 + ln15][32 + quad * 8];

  float mrow[4] = {-3.0e38f, -3.0e38f, -3.0e38f, -3.0e38f};
  float lrow[4] = {0.f, 0.f, 0.f, 0.f};
  f4_t  oacc[4];
  #pragma unroll
  for (int f = 0; f < 4; ++f) oacc[f] = (f4_t){0.f, 0.f, 0.f, 0.f};

  for (int kc = 0; kc < SLEN; kc += 64) {
    __syncthreads();
    // ---- stage K chunk (natural [kcol][d]) ----
    {
      const float* src = k + qkbase + (size_t)(kc + srow) * 1024 + sc0;
      float4 f0 = ((const float4*)src)[0];
      float4 f1 = ((const float4*)src)[1];
      float4 f2 = ((const float4*)src)[2];
      float4 f3 = ((const float4*)src)[3];
      stage16(f0, f1, f2, f3, &Ks[srow][sc0]);
    }
    // ---- stage V^T chunk (Vs[d][kc_local]) ----
    {
      const float* src = vt + vtbase + (size_t)srow * SLEN + kc + sc0;
      float4 f0 = ((const float4*)src)[0];
      float4 f1 = ((const float4*)src)[1];
      float4 f2 = ((const float4*)src)[2];
      float4 f3 = ((const float4*)src)[3];
      stage16(f0, f1, f2, f3, &Vs[srow][sc0]);
    }
    // ---- stage mask bias ----
    {
      const int* msrc = masks + mbase + (size_t)(s0 + srow) * SLEN + kc + sc0;
      int4 m0 = ((const int4*)msrc)[0];
      int4 m1 = ((const int4*)msrc)[1];
      int4 m2 = ((const int4*)msrc)[2];
      int4 m3 = ((const int4*)msrc)[3];
      float4 f0 = {m0.x ? 0.f : -1e9f, m0.y ? 0.f : -1e9f, m0.z ? 0.f : -1e9f, m0.w ? 0.f : -1e9f};
      float4 f1 = {m1.x ? 0.f : -1e9f, m1.y ? 0.f : -1e9f, m1.z ? 0.f : -1e9f, m1.w ? 0.f : -1e9f};
      float4 f2 = {m2.x ? 0.f : -1e9f, m2.y ? 0.f : -1e9f, m2.z ? 0.f : -1e9f, m2.w ? 0.f : -1e9f};
      float4 f3 = {m3.x ? 0.f : -1e9f, m3.y ? 0.f : -1e9f, m3.z ? 0.f : -1e9f, m3.w ? 0.f : -1e9f};
      stage16(f0, f1, f2, f3, &Ms[srow][sc0]);
    }
    __syncthreads();

    // ---- S = Q K^T (16 q-rows x 64 k-cols per wave) ----
    f4_t s[4];
    #pragma unroll
    for (int f = 0; f < 4; ++f) {
      bf8_t bk0 = *(bf8_t*)&Ks[f * 16 + ln15][quad * 8];
      bf8_t bk1 = *(bf8_t*)&Ks[f * 16 + ln15][32 + quad * 8];
      f4_t acc = (f4_t){0.f, 0.f, 0.f, 0.f};
      acc = MFMA16(aq0, bk0, acc);
      acc = MFMA16(aq1, bk1, acc);
      s[f] = acc;
    }
    // ---- scale + mask bias ----
    float sv[4][4];
    #pragma unroll
    for (int f = 0; f < 4; ++f)
      #pragma unroll
      for (int r = 0; r < 4; ++r)
        sv[f][r] = s[f][r] * 0.125f +
                   (float)Ms[wq * 16 + quad * 4 + r][f * 16 + ln15];
    // ---- online softmax update ----
    float alpha[4], rsum[4];
    #pragma unroll
    for (int r = 0; r < 4; ++r) {
      float v = fmaxf(fmaxf(sv[0][r], sv[1][r]), fmaxf(sv[2][r], sv[3][r]));
      v = fmaxf(v, __shfl_xor(v, 1));
      v = fmaxf(v, __shfl_xor(v, 2));
      v = fmaxf(v, __shfl_xor(v, 4));
      v = fmaxf(v, __shfl_xor(v, 8));
      float mn = fmaxf(mrow[r], v);
      alpha[r] = __expf(mrow[r] - mn);
      mrow[r]  = mn;
      rsum[r]  = 0.f;
    }
    #pragma unroll
    for (int f = 0; f < 4; ++f)
      #pragma unroll
      for (int r = 0; r < 4; ++r) {
        float p = __expf(sv[f][r] - mrow[r]);
        rsum[r] += p;
        Pb[wq][quad * 4 + r][f * 16 + ln15] = (__bf16)p;
      }
    #pragma unroll
    for (int r = 0; r < 4; ++r) {
      float sm = rsum[r];
      sm += __shfl_xor(sm, 1);
      sm += __shfl_xor(sm, 2);
      sm += __shfl_xor(sm, 4);
      sm += __shfl_xor(sm, 8);
      lrow[r] = lrow[r] * alpha[r] + sm;
    }
    #pragma unroll
    for (int f = 0; f < 4; ++f) {
      f4_t o = oacc[f];
      o[0] *= alpha[0]; o[1] *= alpha[1]; o[2] *= alpha[2]; o[3] *= alpha[3];
      oacc[f] = o;
    }
    // ---- O += P V ----
    bf8_t ap0 = *(bf8_t*)&Pb[wq][ln15][quad * 8];
    bf8_t ap1 = *(bf8_t*)&Pb[wq][ln15][32 + quad * 8];
    #pragma unroll
    for (int f = 0; f < 4; ++f) {
      bf8_t bv0 = *(bf8_t*)&Vs[f * 16 + ln15][quad * 8];
      bf8_t bv1 = *(bf8_t*)&Vs[f * 16 + ln15][32 + quad * 8];
      f4_t o = oacc[f];
      o = MFMA16(ap0, bv0, o);
      o = MFMA16(ap1, bv1, o);
      oacc[f] = o;
    }
  }

  // ---- epilogue: normalize and write ----
  #pragma unroll
  for (int f = 0; f < 4; ++f)
    #pragma unroll
    for (int r = 0; r < 4; ++r) {
      size_t row = s0 + wq * 16 + quad * 4 + r;
      out[qkbase + row * 1024 + f * 16 + ln15] = oacc[f][r] / lrow[r];
    }
}

// ---------------------------------------------------------------------------
extern "C" void kernel_launch(void* const* d_in, const int* in_sizes, int n_in,
                              void* d_out, int out_size, void* d_ws, size_t ws_size,
                              hipStream_t stream) {
  const float* x     = (const float*)d_in[0];
  const int*   masks = (const int*)d_in[1];
  const int*   Hm    = (const int*)d_in[2];
  const int*   Bm    = (const int*)d_in[3];
  const float* fc    = (const float*)d_in[4];
  const float* fs    = (const float*)d_in[5];
  const float* wq    = (const float*)d_in[6];
  const float* wk    = (const float*)d_in[7];
  const float* wv    = (const float*)d_in[8];
  const float* wo    = (const float*)d_in[9];
  float* out = (float*)d_out;

  float* q  = (float*)d_ws;
  float* k  = q + 2097152;
  float* vt = k + 2097152;   // transposed: vt[b*1024 + d_global][s]
  float* ao = vt + 2097152;

  dim3 blk(256);
  gemm_qkv<<<dim3(16, 32, 3), blk, 0, stream>>>(x, wq, wk, wv, q, k, vt);
  rope_kernel<<<dim3(128, 2), blk, 0, stream>>>(q, k, Hm, Bm, fc, fs);
  attn_mfma<<<dim3(16, 32), blk, 0, stream>>>(q, k, vt, masks, ao);
  gemm_o<<<dim3(16, 32), blk, 0, stream>>>(ao, wo, out);
}

// Round 3
// 210.046 us; speedup vs baseline: 3.7333x; 1.9803x over previous
//
#include <hip/hip_runtime.h>

#define SLEN 1024
#define BATCH 2
#define DEPTH 6

typedef _Float16 h8 __attribute__((ext_vector_type(8)));
typedef float    f4 __attribute__((ext_vector_type(4)));
#define MF16(a, b, c) __builtin_amdgcn_mfma_f32_16x16x32_f16(a, b, c, 0, 0, 0)

// ---------------------------------------------------------------------------
// Converts
// ---------------------------------------------------------------------------
__global__ __launch_bounds__(256) void conv_x(const float* __restrict__ x,
                                              _Float16* __restrict__ xh) {
  int idx = (blockIdx.x * 256 + threadIdx.x) * 8;
  float4 f0 = *(const float4*)(x + idx);
  float4 f1 = *(const float4*)(x + idx + 4);
  union { h8 v; _Float16 e[8]; } u;
  u.e[0] = (_Float16)f0.x; u.e[1] = (_Float16)f0.y;
  u.e[2] = (_Float16)f0.z; u.e[3] = (_Float16)f0.w;
  u.e[4] = (_Float16)f1.x; u.e[5] = (_Float16)f1.y;
  u.e[6] = (_Float16)f1.z; u.e[7] = (_Float16)f1.w;
  *(h8*)(xh + idx) = u.v;
}

// Wt[n][k] = (fp16) W[k][n]   (64x64 tiles through LDS)
__global__ __launch_bounds__(256) void conv_wt(const float* __restrict__ wq,
    const float* __restrict__ wk, const float* __restrict__ wv,
    const float* __restrict__ wo, _Float16* __restrict__ qt,
    _Float16* __restrict__ kt, _Float16* __restrict__ vt,
    _Float16* __restrict__ ot) {
  const float* W = blockIdx.z == 0 ? wq : blockIdx.z == 1 ? wk
                 : blockIdx.z == 2 ? wv : wo;
  _Float16* O = blockIdx.z == 0 ? qt : blockIdx.z == 1 ? kt
              : blockIdx.z == 2 ? vt : ot;
  __shared__ _Float16 T[64][72];
  const int t = threadIdx.x;
  const int k0 = blockIdx.y * 64, n0 = blockIdx.x * 64;
  const int rr = t >> 2, cs = (t & 3) * 16;
  #pragma unroll
  for (int i = 0; i < 4; ++i) {
    float4 f = *(const float4*)(W + (size_t)(k0 + rr) * 1024 + n0 + cs + i * 4);
    T[rr][cs + i * 4 + 0] = (_Float16)f.x;
    T[rr][cs + i * 4 + 1] = (_Float16)f.y;
    T[rr][cs + i * 4 + 2] = (_Float16)f.z;
    T[rr][cs + i * 4 + 3] = (_Float16)f.w;
  }
  __syncthreads();
  const int n = t >> 2, ks = (t & 3) * 16;
  union { h8 v; _Float16 e[8]; } u0, u1;
  #pragma unroll
  for (int i = 0; i < 8; ++i) { u0.e[i] = T[ks + i][n]; u1.e[i] = T[ks + 8 + i][n]; }
  *(h8*)(O + (size_t)(n0 + n) * 1024 + k0 + ks)     = u0.v;
  *(h8*)(O + (size_t)(n0 + n) * 1024 + k0 + ks + 8) = u1.v;
}

// ---------------------------------------------------------------------------
// fp16 MFMA GEMM: C[M,1024] = A[M,1024] @ Bt^T   (Bt is [n][k] fp16)
// 128x128 tile, BK=64, 4 waves x 64x64.  TMODE1: vt[(m>>10)*1024+n][m&1023]
// ---------------------------------------------------------------------------
template <int TMODE>
__device__ __forceinline__ void gemm16(const _Float16* __restrict__ A,
                                       const _Float16* __restrict__ Bt,
                                       float* __restrict__ C) {
  __shared__ _Float16 As[128][72];
  __shared__ _Float16 Bs[128][72];
  const int t    = threadIdx.x;
  const int bm   = blockIdx.y * 128, bn = blockIdx.x * 128;
  const int w    = t >> 6, lane = t & 63;
  const int ln15 = lane & 15, quad = lane >> 4;
  const int wm   = (w >> 1) * 64, wn = (w & 1) * 64;
  const int sc   = t & 7, sr = t >> 3;   // chunk 0..7, rowgroup 0..31
  f4 acc[4][4];
  #pragma unroll
  for (int i = 0; i < 4; ++i)
    #pragma unroll
    for (int j = 0; j < 4; ++j) acc[i][j] = (f4){0.f, 0.f, 0.f, 0.f};

  for (int k0 = 0; k0 < 1024; k0 += 64) {
    h8 ar[4], br[4];
    #pragma unroll
    for (int j = 0; j < 4; ++j) {
      ar[j] = *(const h8*)(A  + (size_t)(bm + sr + j * 32) * 1024 + k0 + sc * 8);
      br[j] = *(const h8*)(Bt + (size_t)(bn + sr + j * 32) * 1024 + k0 + sc * 8);
    }
    __syncthreads();
    #pragma unroll
    for (int j = 0; j < 4; ++j) {
      *(h8*)&As[sr + j * 32][sc * 8] = ar[j];
      *(h8*)&Bs[sr + j * 32][sc * 8] = br[j];
    }
    __syncthreads();
    #pragma unroll
    for (int kk = 0; kk < 64; kk += 32) {
      h8 af[4], bf[4];
      #pragma unroll
      for (int i = 0; i < 4; ++i) af[i] = *(const h8*)&As[wm + i * 16 + ln15][kk + quad * 8];
      #pragma unroll
      for (int j = 0; j < 4; ++j) bf[j] = *(const h8*)&Bs[wn + j * 16 + ln15][kk + quad * 8];
      #pragma unroll
      for (int i = 0; i < 4; ++i)
        #pragma unroll
        for (int j = 0; j < 4; ++j)
          acc[i][j] = MF16(af[i], bf[j], acc[i][j]);
    }
  }
  if (TMODE == 0) {
    #pragma unroll
    for (int i = 0; i < 4; ++i) {
      int row = bm + wm + i * 16 + quad * 4;
      #pragma unroll
      for (int r = 0; r < 4; ++r)
        #pragma unroll
        for (int j = 0; j < 4; ++j)
          C[(size_t)(row + r) * 1024 + bn + wn + j * 16 + ln15] = acc[i][j][r];
    }
  } else {
    #pragma unroll
    for (int i = 0; i < 4; ++i) {
      int m0 = bm + wm + i * 16 + quad * 4;
      #pragma unroll
      for (int r = 0; r < 4; ++r) {
        int m = m0 + r;
        size_t base = ((size_t)(m >> 10) * 1024) * 1024 + (m & 1023);
        #pragma unroll
        for (int j = 0; j < 4; ++j)
          C[base + (size_t)(bn + wn + j * 16 + ln15) * 1024] = acc[i][j][r];
      }
    }
  }
}

__global__ __launch_bounds__(256) void gemm_qkv16(const _Float16* __restrict__ xh,
    const _Float16* __restrict__ qt, const _Float16* __restrict__ kt,
    const _Float16* __restrict__ vtw, float* __restrict__ q,
    float* __restrict__ k, float* __restrict__ vt) {
  if (blockIdx.z == 2)      gemm16<1>(xh, vtw, vt);
  else if (blockIdx.z == 1) gemm16<0>(xh, kt, k);
  else                      gemm16<0>(xh, qt, q);
}

__global__ __launch_bounds__(256) void gemm_o16(const _Float16* __restrict__ A,
    const _Float16* __restrict__ Bt, float* __restrict__ C) {
  gemm16<0>(A, Bt, C);
}

// ---------------------------------------------------------------------------
// RoPE instruction sequence (fp32, unchanged)
// ---------------------------------------------------------------------------
__global__ __launch_bounds__(256) void rope_kernel(float* __restrict__ q,
    float* __restrict__ k, const int* __restrict__ Hm,
    const int* __restrict__ Bm, const float* __restrict__ fc,
    const float* __restrict__ fs) {
  __shared__ float c1[32], s1[32], c2[32], s2[32];
  const int t = threadIdx.x;
  if (t < 32) {
    c1[t] = fc[32 + t]; s1[t] = fs[32 + t];
    c2[t] = fc[64 + t]; s2[t] = fs[64 + t];
  }
  __syncthreads();
  const int gid = blockIdx.x * 256 + t;
  const int bs  = gid >> 4;
  float* base = (blockIdx.y == 0 ? q : k) + (size_t)gid * 64;
  float vv[64];
  #pragma unroll
  for (int i = 0; i < 16; ++i) *(float4*)&vv[i * 4] = *(const float4*)(base + i * 4);
  #pragma unroll 1
  for (int d = 0; d < DEPTH; ++d) {
    if (Hm[d * (BATCH * SLEN) + bs] != 0) {
      #pragma unroll
      for (int j = 0; j < 32; ++j) {
        float re = vv[2 * j], im = vv[2 * j + 1];
        vv[2 * j]     = re * c1[j] - im * s1[j];
        vv[2 * j + 1] = re * s1[j] + im * c1[j];
      }
    }
    if (Bm[(d * 2 + 0) * (BATCH * SLEN) + bs] != 0) {
      #pragma unroll
      for (int j = 0; j < 32; ++j) {
        float re = vv[j], im = vv[j + 32];
        vv[j]      = re * c1[j] - im * s1[j];
        vv[j + 32] = re * s1[j] + im * c1[j];
      }
    }
    if (Bm[(d * 2 + 1) * (BATCH * SLEN) + bs] != 0) {
      #pragma unroll
      for (int j = 0; j < 32; ++j) {
        float re = vv[j], im = vv[j + 32];
        vv[j]      = re * c2[j] - im * s2[j];
        vv[j + 32] = re * s2[j] + im * c2[j];
      }
    }
  }
  #pragma unroll
  for (int i = 0; i < 16; ++i) *(float4*)(base + i * 4) = *(const float4*)&vv[i * 4];
}

// ---------------------------------------------------------------------------
// MFMA flash attention (fp16). Block = (b,h,64 q-rows); 4 waves x 16 q-rows.
// Output written as fp16 (feeds gemm_o16 directly).
// ---------------------------------------------------------------------------
__device__ __forceinline__ void stg16(float4 f0, float4 f1, float4 f2,
                                      float4 f3, _Float16* dst) {
  union { h8 v; _Float16 e[8]; } a, b;
  a.e[0] = (_Float16)f0.x; a.e[1] = (_Float16)f0.y;
  a.e[2] = (_Float16)f0.z; a.e[3] = (_Float16)f0.w;
  a.e[4] = (_Float16)f1.x; a.e[5] = (_Float16)f1.y;
  a.e[6] = (_Float16)f1.z; a.e[7] = (_Float16)f1.w;
  b.e[0] = (_Float16)f2.x; b.e[1] = (_Float16)f2.y;
  b.e[2] = (_Float16)f2.z; b.e[3] = (_Float16)f2.w;
  b.e[4] = (_Float16)f3.x; b.e[5] = (_Float16)f3.y;
  b.e[6] = (_Float16)f3.z; b.e[7] = (_Float16)f3.w;
  *(h8*)dst       = a.v;
  *(h8*)(dst + 8) = b.v;
}

__global__ __launch_bounds__(256) void attn_mfma(const float* __restrict__ q,
    const float* __restrict__ k, const float* __restrict__ vt,
    const int* __restrict__ masks, _Float16* __restrict__ out) {
  __shared__ _Float16 Qs[64][72];
  __shared__ _Float16 Ks[64][72];
  __shared__ _Float16 Vs[64][72];      // Vs[d][kc_local]
  __shared__ _Float16 Ms[64][72];      // additive bias: 0 or -30000
  __shared__ _Float16 Pb[4][16][72];   // wave-private P

  const int t    = threadIdx.x;
  const int wq   = t >> 6;
  const int lane = t & 63;
  const int ln15 = lane & 15;
  const int quad = lane >> 4;

  const int b  = blockIdx.y >> 4;
  const int h  = blockIdx.y & 15;
  const int s0 = blockIdx.x * 64;

  const size_t qkbase = (size_t)b * (SLEN * 1024) + (size_t)h * 64;
  const size_t vtbase = ((size_t)b * 1024 + h * 64) * SLEN;
  const size_t mbase  = (size_t)b * SLEN * SLEN;

  const int srow = t >> 2;
  const int sc0  = (t & 3) * 16;

  {
    const float* src = q + qkbase + (size_t)(s0 + srow) * 1024 + sc0;
    stg16(((const float4*)src)[0], ((const float4*)src)[1],
          ((const float4*)src)[2], ((const float4*)src)[3], &Qs[srow][sc0]);
  }
  __syncthreads();
  h8 aq0 = *(h8*)&Qs[wq * 16 + ln15][quad * 8];
  h8 aq1 = *(h8*)&Qs[wq * 16 + ln15][32 + quad * 8];

  float mrow[4] = {-3.0e38f, -3.0e38f, -3.0e38f, -3.0e38f};
  float lrow[4] = {0.f, 0.f, 0.f, 0.f};
  f4 oacc[4];
  #pragma unroll
  for (int f = 0; f < 4; ++f) oacc[f] = (f4){0.f, 0.f, 0.f, 0.f};

  for (int kc = 0; kc < SLEN; kc += 64) {
    __syncthreads();
    {
      const float* src = k + qkbase + (size_t)(kc + srow) * 1024 + sc0;
      stg16(((const float4*)src)[0], ((const float4*)src)[1],
            ((const float4*)src)[2], ((const float4*)src)[3], &Ks[srow][sc0]);
    }
    {
      const float* src = vt + vtbase + (size_t)srow * SLEN + kc + sc0;
      stg16(((const float4*)src)[0], ((const float4*)src)[1],
            ((const float4*)src)[2], ((const float4*)src)[3], &Vs[srow][sc0]);
    }
    {
      const int* msrc = masks + mbase + (size_t)(s0 + srow) * SLEN + kc + sc0;
      int4 m0 = ((const int4*)msrc)[0];
      int4 m1 = ((const int4*)msrc)[1];
      int4 m2 = ((const int4*)msrc)[2];
      int4 m3 = ((const int4*)msrc)[3];
      float4 f0 = {m0.x ? 0.f : -30000.f, m0.y ? 0.f : -30000.f, m0.z ? 0.f : -30000.f, m0.w ? 0.f : -30000.f};
      float4 f1 = {m1.x ? 0.f : -30000.f, m1.y ? 0.f : -30000.f, m1.z ? 0.f : -30000.f, m1.w ? 0.f : -30000.f};
      float4 f2 = {m2.x ? 0.f : -30000.f, m2.y ? 0.f : -30000.f, m2.z ? 0.f : -30000.f, m2.w ? 0.f : -30000.f};
      float4 f3 = {m3.x ? 0.f : -30000.f, m3.y ? 0.f : -30000.f, m3.z ? 0.f : -30000.f, m3.w ? 0.f : -30000.f};
      stg16(f0, f1, f2, f3, &Ms[srow][sc0]);
    }
    __syncthreads();

    f4 s[4];
    #pragma unroll
    for (int f = 0; f < 4; ++f) {
      h8 bk0 = *(h8*)&Ks[f * 16 + ln15][quad * 8];
      h8 bk1 = *(h8*)&Ks[f * 16 + ln15][32 + quad * 8];
      f4 acc = (f4){0.f, 0.f, 0.f, 0.f};
      acc = MF16(aq0, bk0, acc);
      acc = MF16(aq1, bk1, acc);
      s[f] = acc;
    }
    float sv[4][4];
    #pragma unroll
    for (int f = 0; f < 4; ++f)
      #pragma unroll
      for (int r = 0; r < 4; ++r)
        sv[f][r] = s[f][r] * 0.125f +
                   (float)Ms[wq * 16 + quad * 4 + r][f * 16 + ln15];
    float alpha[4], rsum[4];
    #pragma unroll
    for (int r = 0; r < 4; ++r) {
      float v = fmaxf(fmaxf(sv[0][r], sv[1][r]), fmaxf(sv[2][r], sv[3][r]));
      v = fmaxf(v, __shfl_xor(v, 1));
      v = fmaxf(v, __shfl_xor(v, 2));
      v = fmaxf(v, __shfl_xor(v, 4));
      v = fmaxf(v, __shfl_xor(v, 8));
      float mn = fmaxf(mrow[r], v);
      alpha[r] = __expf(mrow[r] - mn);
      mrow[r]  = mn;
      rsum[r]  = 0.f;
    }
    #pragma unroll
    for (int f = 0; f < 4; ++f)
      #pragma unroll
      for (int r = 0; r < 4; ++r) {
        float p = __expf(sv[f][r] - mrow[r]);
        rsum[r] += p;
        Pb[wq][quad * 4 + r][f * 16 + ln15] = (_Float16)p;
      }
    #pragma unroll
    for (int r = 0; r < 4; ++r) {
      float sm = rsum[r];
      sm += __shfl_xor(sm, 1);
      sm += __shfl_xor(sm, 2);
      sm += __shfl_xor(sm, 4);
      sm += __shfl_xor(sm, 8);
      lrow[r] = lrow[r] * alpha[r] + sm;
    }
    #pragma unroll
    for (int f = 0; f < 4; ++f) {
      f4 o = oacc[f];
      o[0] *= alpha[0]; o[1] *= alpha[1]; o[2] *= alpha[2]; o[3] *= alpha[3];
      oacc[f] = o;
    }
    h8 ap0 = *(h8*)&Pb[wq][ln15][quad * 8];
    h8 ap1 = *(h8*)&Pb[wq][ln15][32 + quad * 8];
    #pragma unroll
    for (int f = 0; f < 4; ++f) {
      h8 bv0 = *(h8*)&Vs[f * 16 + ln15][quad * 8];
      h8 bv1 = *(h8*)&Vs[f * 16 + ln15][32 + quad * 8];
      f4 o = oacc[f];
      o = MF16(ap0, bv0, o);
      o = MF16(ap1, bv1, o);
      oacc[f] = o;
    }
  }

  #pragma unroll
  for (int f = 0; f < 4; ++f)
    #pragma unroll
    for (int r = 0; r < 4; ++r) {
      size_t row = s0 + wq * 16 + quad * 4 + r;
      out[qkbase + row * 1024 + f * 16 + ln15] = (_Float16)(oacc[f][r] / lrow[r]);
    }
}

// ---------------------------------------------------------------------------
extern "C" void kernel_launch(void* const* d_in, const int* in_sizes, int n_in,
                              void* d_out, int out_size, void* d_ws, size_t ws_size,
                              hipStream_t stream) {
  const float* x     = (const float*)d_in[0];
  const int*   masks = (const int*)d_in[1];
  const int*   Hm    = (const int*)d_in[2];
  const int*   Bm    = (const int*)d_in[3];
  const float* fc    = (const float*)d_in[4];
  const float* fs    = (const float*)d_in[5];
  const float* wq    = (const float*)d_in[6];
  const float* wk    = (const float*)d_in[7];
  const float* wv    = (const float*)d_in[8];
  const float* wo    = (const float*)d_in[9];
  float* out = (float*)d_out;

  float* q  = (float*)d_ws;
  float* k  = q + (1 << 21);
  float* vt = k + (1 << 21);
  _Float16* xh  = (_Float16*)(vt + (1 << 21));
  _Float16* wqt = xh  + (1 << 21);
  _Float16* wkt = wqt + (1 << 20);
  _Float16* wvt = wkt + (1 << 20);
  _Float16* wot = wvt + (1 << 20);
  _Float16* aoh = wot + (1 << 20);

  dim3 blk(256);
  conv_x<<<dim3(1024), blk, 0, stream>>>(x, xh);
  conv_wt<<<dim3(16, 16, 4), blk, 0, stream>>>(wq, wk, wv, wo, wqt, wkt, wvt, wot);
  gemm_qkv16<<<dim3(8, 16, 3), blk, 0, stream>>>(xh, wqt, wkt, wvt, q, k, vt);
  rope_kernel<<<dim3(128, 2), blk, 0, stream>>>(q, k, Hm, Bm, fc, fs);
  attn_mfma<<<dim3(16, 32), blk, 0, stream>>>(q, k, vt, masks, aoh);
  gemm_o16<<<dim3(8, 16), blk, 0, stream>>>(aoh, wot, out);
}

// Round 4
// 199.123 us; speedup vs baseline: 3.9381x; 1.0549x over previous
//
#include <hip/hip_runtime.h>

#define SLEN 1024
#define BATCH 2
#define DEPTH 6

typedef _Float16 h8 __attribute__((ext_vector_type(8)));
typedef float    f4 __attribute__((ext_vector_type(4)));
#define MF16(a, b, c) __builtin_amdgcn_mfma_f32_16x16x32_f16(a, b, c, 0, 0, 0)

// ---------------------------------------------------------------------------
// prep: blockIdx.x 0..1023 -> x convert; 1024..2047 -> weight transpose+convert
//       2048..3071 -> mask -> fp16 additive bias
// ---------------------------------------------------------------------------
__global__ __launch_bounds__(256) void prep(const float* __restrict__ x,
    const float* __restrict__ wq, const float* __restrict__ wk,
    const float* __restrict__ wv, const float* __restrict__ wo,
    const int* __restrict__ masks, _Float16* __restrict__ xh,
    _Float16* __restrict__ qt, _Float16* __restrict__ kt,
    _Float16* __restrict__ vt, _Float16* __restrict__ ot,
    _Float16* __restrict__ bias) {
  __shared__ _Float16 T[64][72];
  const int bid = blockIdx.x, t = threadIdx.x;
  if (bid < 1024) {
    int idx = (bid * 256 + t) * 8;
    float4 f0 = *(const float4*)(x + idx);
    float4 f1 = *(const float4*)(x + idx + 4);
    union { h8 v; _Float16 e[8]; } u;
    u.e[0] = (_Float16)f0.x; u.e[1] = (_Float16)f0.y;
    u.e[2] = (_Float16)f0.z; u.e[3] = (_Float16)f0.w;
    u.e[4] = (_Float16)f1.x; u.e[5] = (_Float16)f1.y;
    u.e[6] = (_Float16)f1.z; u.e[7] = (_Float16)f1.w;
    *(h8*)(xh + idx) = u.v;
  } else if (bid < 2048) {
    const int i = bid - 1024;
    const int wsel = i >> 8;
    const float* W = wsel == 0 ? wq : wsel == 1 ? wk : wsel == 2 ? wv : wo;
    _Float16* O = wsel == 0 ? qt : wsel == 1 ? kt : wsel == 2 ? vt : ot;
    const int k0 = ((i >> 4) & 15) * 64, n0 = (i & 15) * 64;
    const int rr = t >> 2, cs = (t & 3) * 16;
    #pragma unroll
    for (int j = 0; j < 4; ++j) {
      float4 f = *(const float4*)(W + (size_t)(k0 + rr) * 1024 + n0 + cs + j * 4);
      T[rr][cs + j * 4 + 0] = (_Float16)f.x;
      T[rr][cs + j * 4 + 1] = (_Float16)f.y;
      T[rr][cs + j * 4 + 2] = (_Float16)f.z;
      T[rr][cs + j * 4 + 3] = (_Float16)f.w;
    }
    __syncthreads();
    const int n = t >> 2, ks = (t & 3) * 16;
    union { h8 v; _Float16 e[8]; } u0, u1;
    #pragma unroll
    for (int j = 0; j < 8; ++j) { u0.e[j] = T[ks + j][n]; u1.e[j] = T[ks + 8 + j][n]; }
    *(h8*)(O + (size_t)(n0 + n) * 1024 + k0 + ks)     = u0.v;
    *(h8*)(O + (size_t)(n0 + n) * 1024 + k0 + ks + 8) = u1.v;
  } else {
    const int i = bid - 2048;
    int idx = i * 2048 + t * 8;
    int4 m0 = *(const int4*)(masks + idx);
    int4 m1 = *(const int4*)(masks + idx + 4);
    union { h8 v; _Float16 e[8]; } u;
    u.e[0] = m0.x ? (_Float16)0.f : (_Float16)-30000.f;
    u.e[1] = m0.y ? (_Float16)0.f : (_Float16)-30000.f;
    u.e[2] = m0.z ? (_Float16)0.f : (_Float16)-30000.f;
    u.e[3] = m0.w ? (_Float16)0.f : (_Float16)-30000.f;
    u.e[4] = m1.x ? (_Float16)0.f : (_Float16)-30000.f;
    u.e[5] = m1.y ? (_Float16)0.f : (_Float16)-30000.f;
    u.e[6] = m1.z ? (_Float16)0.f : (_Float16)-30000.f;
    u.e[7] = m1.w ? (_Float16)0.f : (_Float16)-30000.f;
    *(h8*)(bias + idx) = u.v;
  }
}

// ---------------------------------------------------------------------------
// fp16 MFMA GEMM: C[M,1024] = A[M,1024] @ Bt^T   (Bt is [n][k] fp16)
// 128x128 tile, BK=64, 4 waves x 64x64.
// TMODE0: row-major CT C.  TMODE1: CT vt[(m>>10)*1024+n][m&1023]
// ---------------------------------------------------------------------------
template <int TMODE, typename CT>
__device__ __forceinline__ void gemm16(const _Float16* __restrict__ A,
                                       const _Float16* __restrict__ Bt,
                                       CT* __restrict__ C) {
  __shared__ _Float16 As[128][72];
  __shared__ _Float16 Bs[128][72];
  const int t    = threadIdx.x;
  const int bm   = blockIdx.y * 128, bn = blockIdx.x * 128;
  const int w    = t >> 6, lane = t & 63;
  const int ln15 = lane & 15, quad = lane >> 4;
  const int wm   = (w >> 1) * 64, wn = (w & 1) * 64;
  const int sc   = t & 7, sr = t >> 3;
  f4 acc[4][4];
  #pragma unroll
  for (int i = 0; i < 4; ++i)
    #pragma unroll
    for (int j = 0; j < 4; ++j) acc[i][j] = (f4){0.f, 0.f, 0.f, 0.f};

  for (int k0 = 0; k0 < 1024; k0 += 64) {
    h8 ar[4], br[4];
    #pragma unroll
    for (int j = 0; j < 4; ++j) {
      ar[j] = *(const h8*)(A  + (size_t)(bm + sr + j * 32) * 1024 + k0 + sc * 8);
      br[j] = *(const h8*)(Bt + (size_t)(bn + sr + j * 32) * 1024 + k0 + sc * 8);
    }
    __syncthreads();
    #pragma unroll
    for (int j = 0; j < 4; ++j) {
      *(h8*)&As[sr + j * 32][sc * 8] = ar[j];
      *(h8*)&Bs[sr + j * 32][sc * 8] = br[j];
    }
    __syncthreads();
    #pragma unroll
    for (int kk = 0; kk < 64; kk += 32) {
      h8 af[4], bf[4];
      #pragma unroll
      for (int i = 0; i < 4; ++i) af[i] = *(const h8*)&As[wm + i * 16 + ln15][kk + quad * 8];
      #pragma unroll
      for (int j = 0; j < 4; ++j) bf[j] = *(const h8*)&Bs[wn + j * 16 + ln15][kk + quad * 8];
      #pragma unroll
      for (int i = 0; i < 4; ++i)
        #pragma unroll
        for (int j = 0; j < 4; ++j)
          acc[i][j] = MF16(af[i], bf[j], acc[i][j]);
    }
  }
  if (TMODE == 0) {
    #pragma unroll
    for (int i = 0; i < 4; ++i) {
      int row = bm + wm + i * 16 + quad * 4;
      #pragma unroll
      for (int r = 0; r < 4; ++r)
        #pragma unroll
        for (int j = 0; j < 4; ++j)
          C[(size_t)(row + r) * 1024 + bn + wn + j * 16 + ln15] = (CT)acc[i][j][r];
    }
  } else {
    #pragma unroll
    for (int i = 0; i < 4; ++i) {
      int m0 = bm + wm + i * 16 + quad * 4;
      #pragma unroll
      for (int r = 0; r < 4; ++r) {
        int m = m0 + r;
        size_t base = ((size_t)(m >> 10) * 1024) * 1024 + (m & 1023);
        #pragma unroll
        for (int j = 0; j < 4; ++j)
          C[base + (size_t)(bn + wn + j * 16 + ln15) * 1024] = (CT)acc[i][j][r];
      }
    }
  }
}

__global__ __launch_bounds__(256) void gemm_qkv16(const _Float16* __restrict__ xh,
    const _Float16* __restrict__ qt, const _Float16* __restrict__ kt,
    const _Float16* __restrict__ vtw, float* __restrict__ q,
    float* __restrict__ k, _Float16* __restrict__ vth) {
  if (blockIdx.z == 2)      gemm16<1, _Float16>(xh, vtw, vth);
  else if (blockIdx.z == 1) gemm16<0, float>(xh, kt, k);
  else                      gemm16<0, float>(xh, qt, q);
}

__global__ __launch_bounds__(256) void gemm_o16(const _Float16* __restrict__ A,
    const _Float16* __restrict__ Bt, float* __restrict__ C) {
  gemm16<0, float>(A, Bt, C);
}

// ---------------------------------------------------------------------------
// RoPE: fp32 in (q,k from GEMM), fp32 math, fp16 out (qh,kh)
// ---------------------------------------------------------------------------
__global__ __launch_bounds__(256) void rope_kernel(const float* __restrict__ q,
    const float* __restrict__ k, _Float16* __restrict__ qh,
    _Float16* __restrict__ kh, const int* __restrict__ Hm,
    const int* __restrict__ Bm, const float* __restrict__ fc,
    const float* __restrict__ fs) {
  __shared__ float c1[32], s1[32], c2[32], s2[32];
  const int t = threadIdx.x;
  if (t < 32) {
    c1[t] = fc[32 + t]; s1[t] = fs[32 + t];
    c2[t] = fc[64 + t]; s2[t] = fs[64 + t];
  }
  __syncthreads();
  const int gid = blockIdx.x * 256 + t;
  const int bs  = gid >> 4;
  const float* src = (blockIdx.y == 0 ? q : k) + (size_t)gid * 64;
  _Float16*    dst = (blockIdx.y == 0 ? qh : kh) + (size_t)gid * 64;
  float vv[64];
  #pragma unroll
  for (int i = 0; i < 16; ++i) *(float4*)&vv[i * 4] = *(const float4*)(src + i * 4);
  #pragma unroll 1
  for (int d = 0; d < DEPTH; ++d) {
    if (Hm[d * (BATCH * SLEN) + bs] != 0) {
      #pragma unroll
      for (int j = 0; j < 32; ++j) {
        float re = vv[2 * j], im = vv[2 * j + 1];
        vv[2 * j]     = re * c1[j] - im * s1[j];
        vv[2 * j + 1] = re * s1[j] + im * c1[j];
      }
    }
    if (Bm[(d * 2 + 0) * (BATCH * SLEN) + bs] != 0) {
      #pragma unroll
      for (int j = 0; j < 32; ++j) {
        float re = vv[j], im = vv[j + 32];
        vv[j]      = re * c1[j] - im * s1[j];
        vv[j + 32] = re * s1[j] + im * c1[j];
      }
    }
    if (Bm[(d * 2 + 1) * (BATCH * SLEN) + bs] != 0) {
      #pragma unroll
      for (int j = 0; j < 32; ++j) {
        float re = vv[j], im = vv[j + 32];
        vv[j]      = re * c2[j] - im * s2[j];
        vv[j + 32] = re * s2[j] + im * c2[j];
      }
    }
  }
  #pragma unroll
  for (int i = 0; i < 8; ++i) {
    union { h8 v; _Float16 e[8]; } u;
    #pragma unroll
    for (int j = 0; j < 8; ++j) u.e[j] = (_Float16)vv[i * 8 + j];
    *(h8*)(dst + i * 8) = u.v;
  }
}

// ---------------------------------------------------------------------------
// MFMA flash attention, fp16 in/out, software-pipelined K loop.
// Block = (b,h,64 q-rows); 4 waves x 16 q-rows. Qs LDS reused as P buffer.
// ---------------------------------------------------------------------------
__global__ __launch_bounds__(256) void attn_mfma(const _Float16* __restrict__ qh,
    const _Float16* __restrict__ kh, const _Float16* __restrict__ vth,
    const _Float16* __restrict__ bias, _Float16* __restrict__ out) {
  __shared__ _Float16 Qs[64][72];   // after prologue: wave-private P buffer
  __shared__ _Float16 Ks[64][72];
  __shared__ _Float16 Vs[64][72];
  __shared__ _Float16 Ms[64][72];

  const int t    = threadIdx.x;
  const int wv   = t >> 6;
  const int lane = t & 63;
  const int ln15 = lane & 15;
  const int quad = lane >> 4;

  const int b  = blockIdx.y >> 4;
  const int h  = blockIdx.y & 15;
  const int s0 = blockIdx.x * 64;

  const size_t qkbase = (size_t)b * (SLEN * 1024) + h * 64;
  const size_t vbase  = ((size_t)b * 1024 + h * 64) * SLEN;
  const size_t bbase  = (size_t)b * SLEN * SLEN;

  const int srow = t >> 2;
  const int sc0  = (t & 3) * 16;

  // ---- stage Q, read fragments ----
  {
    const _Float16* src = qh + qkbase + (size_t)(s0 + srow) * 1024 + sc0;
    *(h8*)&Qs[srow][sc0]     = *(const h8*)src;
    *(h8*)&Qs[srow][sc0 + 8] = *(const h8*)(src + 8);
  }
  __syncthreads();
  h8 aq0 = *(h8*)&Qs[wv * 16 + ln15][quad * 8];
  h8 aq1 = *(h8*)&Qs[wv * 16 + ln15][32 + quad * 8];

  const _Float16* kp = kh + qkbase + (size_t)srow * 1024 + sc0;
  const _Float16* vp = vth + vbase + (size_t)srow * SLEN + sc0;
  const _Float16* mp = bias + bbase + (size_t)(s0 + srow) * SLEN + sc0;

  // ---- prologue: stage chunk 0 ----
  {
    h8 k0a = *(const h8*)kp, k0b = *(const h8*)(kp + 8);
    h8 v0a = *(const h8*)vp, v0b = *(const h8*)(vp + 8);
    h8 m0a = *(const h8*)mp, m0b = *(const h8*)(mp + 8);
    *(h8*)&Ks[srow][sc0] = k0a; *(h8*)&Ks[srow][sc0 + 8] = k0b;
    *(h8*)&Vs[srow][sc0] = v0a; *(h8*)&Vs[srow][sc0 + 8] = v0b;
    *(h8*)&Ms[srow][sc0] = m0a; *(h8*)&Ms[srow][sc0 + 8] = m0b;
  }
  __syncthreads();

  float mrow[4] = {-3.0e38f, -3.0e38f, -3.0e38f, -3.0e38f};
  float lrow[4] = {0.f, 0.f, 0.f, 0.f};
  f4 oacc[4];
  #pragma unroll
  for (int f = 0; f < 4; ++f) oacc[f] = (f4){0.f, 0.f, 0.f, 0.f};

  for (int c = 0; c < 16; ++c) {
    // ---- prefetch next chunk into regs ----
    h8 kn0, kn1, vn0, vn1, mn0, mn1;
    if (c < 15) {
      size_t ko = (size_t)(c + 1) * 64 * 1024;
      int    no = (c + 1) * 64;
      kn0 = *(const h8*)(kp + ko);  kn1 = *(const h8*)(kp + ko + 8);
      vn0 = *(const h8*)(vp + no);  vn1 = *(const h8*)(vp + no + 8);
      mn0 = *(const h8*)(mp + no);  mn1 = *(const h8*)(mp + no + 8);
    }

    // ---- S = Q K^T ----
    f4 s[4];
    #pragma unroll
    for (int f = 0; f < 4; ++f) {
      h8 bk0 = *(h8*)&Ks[f * 16 + ln15][quad * 8];
      h8 bk1 = *(h8*)&Ks[f * 16 + ln15][32 + quad * 8];
      f4 acc = (f4){0.f, 0.f, 0.f, 0.f};
      acc = MF16(aq0, bk0, acc);
      acc = MF16(aq1, bk1, acc);
      s[f] = acc;
    }
    float sv[4][4];
    #pragma unroll
    for (int f = 0; f < 4; ++f)
      #pragma unroll
      for (int r = 0; r < 4; ++r)
        sv[f][r] = s[f][r] * 0.125f +
                   (float)Ms[wv * 16 + quad * 4 + r][f * 16 + ln15];
    // ---- online softmax ----
    float alpha[4], rsum[4];
    #pragma unroll
    for (int r = 0; r < 4; ++r) {
      float v = fmaxf(fmaxf(sv[0][r], sv[1][r]), fmaxf(sv[2][r], sv[3][r]));
      v = fmaxf(v, __shfl_xor(v, 1));
      v = fmaxf(v, __shfl_xor(v, 2));
      v = fmaxf(v, __shfl_xor(v, 4));
      v = fmaxf(v, __shfl_xor(v, 8));
      float mn = fmaxf(mrow[r], v);
      alpha[r] = __expf(mrow[r] - mn);
      mrow[r]  = mn;
      rsum[r]  = 0.f;
    }
    #pragma unroll
    for (int f = 0; f < 4; ++f)
      #pragma unroll
      for (int r = 0; r < 4; ++r) {
        float p = __expf(sv[f][r] - mrow[r]);
        rsum[r] += p;
        Qs[wv * 16 + quad * 4 + r][f * 16 + ln15] = (_Float16)p;
      }
    #pragma unroll
    for (int r = 0; r < 4; ++r) {
      float sm = rsum[r];
      sm += __shfl_xor(sm, 1);
      sm += __shfl_xor(sm, 2);
      sm += __shfl_xor(sm, 4);
      sm += __shfl_xor(sm, 8);
      lrow[r] = lrow[r] * alpha[r] + sm;
    }
    #pragma unroll
    for (int f = 0; f < 4; ++f) {
      f4 o = oacc[f];
      o[0] *= alpha[0]; o[1] *= alpha[1]; o[2] *= alpha[2]; o[3] *= alpha[3];
      oacc[f] = o;
    }
    // ---- O += P V ----
    h8 ap0 = *(h8*)&Qs[wv * 16 + ln15][quad * 8];
    h8 ap1 = *(h8*)&Qs[wv * 16 + ln15][32 + quad * 8];
    #pragma unroll
    for (int f = 0; f < 4; ++f) {
      h8 bv0 = *(h8*)&Vs[f * 16 + ln15][quad * 8];
      h8 bv1 = *(h8*)&Vs[f * 16 + ln15][32 + quad * 8];
      f4 o = oacc[f];
      o = MF16(ap0, bv0, o);
      o = MF16(ap1, bv1, o);
      oacc[f] = o;
    }
    __syncthreads();
    if (c < 15) {
      *(h8*)&Ks[srow][sc0] = kn0; *(h8*)&Ks[srow][sc0 + 8] = kn1;
      *(h8*)&Vs[srow][sc0] = vn0; *(h8*)&Vs[srow][sc0 + 8] = vn1;
      *(h8*)&Ms[srow][sc0] = mn0; *(h8*)&Ms[srow][sc0 + 8] = mn1;
      __syncthreads();
    }
  }

  #pragma unroll
  for (int f = 0; f < 4; ++f)
    #pragma unroll
    for (int r = 0; r < 4; ++r) {
      size_t row = s0 + wv * 16 + quad * 4 + r;
      out[qkbase + row * 1024 + f * 16 + ln15] = (_Float16)(oacc[f][r] / lrow[r]);
    }
}

// ---------------------------------------------------------------------------
extern "C" void kernel_launch(void* const* d_in, const int* in_sizes, int n_in,
                              void* d_out, int out_size, void* d_ws, size_t ws_size,
                              hipStream_t stream) {
  const float* x     = (const float*)d_in[0];
  const int*   masks = (const int*)d_in[1];
  const int*   Hm    = (const int*)d_in[2];
  const int*   Bm    = (const int*)d_in[3];
  const float* fc    = (const float*)d_in[4];
  const float* fs    = (const float*)d_in[5];
  const float* wq    = (const float*)d_in[6];
  const float* wk    = (const float*)d_in[7];
  const float* wv    = (const float*)d_in[8];
  const float* wo    = (const float*)d_in[9];
  float* out = (float*)d_out;

  float* q  = (float*)d_ws;                       // 2M fp32
  float* k  = q + (1 << 21);                      // 2M fp32
  _Float16* xh   = (_Float16*)(k + (1 << 21));    // 2M
  _Float16* wqt  = xh + (1 << 21);                // 1M
  _Float16* wkt  = wqt + (1 << 20);
  _Float16* wvt  = wkt + (1 << 20);
  _Float16* wot  = wvt + (1 << 20);
  _Float16* vth  = wot + (1 << 20);               // 2M
  _Float16* qhh  = vth + (1 << 21);               // 2M
  _Float16* khh  = qhh + (1 << 21);               // 2M
  _Float16* bias = khh + (1 << 21);               // 2M
  _Float16* aoh  = bias + (1 << 21);              // 2M

  dim3 blk(256);
  prep<<<dim3(3072), blk, 0, stream>>>(x, wq, wk, wv, wo, masks,
                                       xh, wqt, wkt, wvt, wot, bias);
  gemm_qkv16<<<dim3(8, 16, 3), blk, 0, stream>>>(xh, wqt, wkt, wvt, q, k, vth);
  rope_kernel<<<dim3(128, 2), blk, 0, stream>>>(q, k, qhh, khh, Hm, Bm, fc, fs);
  attn_mfma<<<dim3(16, 32), blk, 0, stream>>>(qhh, khh, vth, bias, aoh);
  gemm_o16<<<dim3(8, 16), blk, 0, stream>>>(aoh, wot, out);
}